// Round 11
// baseline (468.945 us; speedup 1.0000x reference)
//
#include <hip/hip_runtime.h>
#include <math.h>

#define N_NODES 50000
#define N_EDGES 800000
#define F_INPUT 128
#define HEADS 4
#define DHID 64
#define HID 256          // HEADS*DHID
#define M_PAD 50048      // 782*64 = 391*128
#define SCAN_B 49        // ceil(50000/1024)

typedef _Float16 half8 __attribute__((ext_vector_type(8)));
typedef _Float16 half4 __attribute__((ext_vector_type(4)));
typedef float f32x4 __attribute__((ext_vector_type(4)));

// ---------------- fused hist + prep ----------------

#define EB_BLOCKS ((N_EDGES + 255) / 256)
#define PREP_A 1600000
#define PREP_B (PREP_A + 196608)
#define PREP_C (PREP_B + 10240)
#define PB_BLOCKS ((PREP_C + 255) / 256)

__global__ void hist_prep_kernel(const int* __restrict__ dst, int* __restrict__ counts,
                                 int* __restrict__ rank,
                                 const float* __restrict__ x, _Float16* __restrict__ x16,
                                 const float* __restrict__ W0, const float* __restrict__ WR,
                                 _Float16* __restrict__ WtL0,
                                 const float* __restrict__ W1, _Float16* __restrict__ Wt1,
                                 const float* __restrict__ W2, _Float16* __restrict__ Wt2,
                                 const float* __restrict__ al0, const float* __restrict__ ar0,
                                 const float* __restrict__ al1, const float* __restrict__ ar1,
                                 const float* __restrict__ al2, const float* __restrict__ ar2) {
    if (blockIdx.x < EB_BLOCKS) {
        int e = blockIdx.x * 256 + threadIdx.x;
        if (e < N_EDGES) rank[e] = atomicAdd(&counts[dst[e]], 1);
        return;
    }
    int t = (blockIdx.x - EB_BLOCKS) * 256 + threadIdx.x;
    if (t < PREP_A) {
        f32x4 v = *(const f32x4*)&x[t * 4];
        half4 h = {(_Float16)v.x, (_Float16)v.y, (_Float16)v.z, (_Float16)v.w};
        *(half4*)&x16[(size_t)t * 4] = h;
    } else if (t < PREP_B) {
        int u = t - PREP_A;
        if (u < 65536) {
            int c = u >> 7;
            int k = u & 127;
            float v = (c < 256) ? W0[k * 256 + c] : WR[k * 256 + (c - 256)];
            WtL0[u] = (_Float16)v;
        } else if (u < 131072) {
            int w = u - 65536;
            int c = w >> 8;
            int k = w & 255;
            Wt1[w] = (_Float16)W1[k * 256 + c];
        } else {
            int w = u - 131072;
            int c = w >> 8;
            int k = w & 255;
            Wt2[w] = (_Float16)W2[k * 256 + c];
        }
    } else if (t < PREP_C) {
        int u = t - PREP_B;
        if (u < 2048) {
            int row8 = u >> 7, k = u & 127;
            int h = row8 & 3;
            const float* vec = (row8 < 4) ? al0 : ar0;
            float s = 0.f;
            for (int d = 0; d < 64; d++) s += W0[k * 256 + h * 64 + d] * vec[h * 64 + d];
            WtL0[(512 + row8) * 128 + k] = (_Float16)s;
        } else if (u < 6144) {
            int w = u - 2048;
            int row8 = w >> 8, k = w & 255;
            int h = row8 & 3;
            const float* vec = (row8 < 4) ? al1 : ar1;
            float s = 0.f;
            for (int d = 0; d < 64; d++) s += W1[k * 256 + h * 64 + d] * vec[h * 64 + d];
            Wt1[(256 + row8) * 256 + k] = (_Float16)s;
        } else {
            int w = u - 6144;
            int row8 = w >> 8, k = w & 255;
            int h = row8 & 3;
            const float* vec = (row8 < 4) ? al2 : ar2;
            float s = 0.f;
            for (int d = 0; d < 64; d++) s += W2[k * 256 + h * 64 + d] * vec[h * 64 + d];
            Wt2[(256 + row8) * 256 + k] = (_Float16)s;
        }
    }
}

// ---------------- CSR scan ----------------

__global__ __launch_bounds__(256) void scan1_kernel(const int* __restrict__ counts,
                                                    int* __restrict__ pre,
                                                    int* __restrict__ bsum) {
    __shared__ int buf[256];
    int tid = threadIdx.x;
    int idx = blockIdx.x * 1024 + tid * 4;
    int v0 = 0, v1 = 0, v2 = 0, v3 = 0;
    if (idx + 3 < N_NODES) {
        int4 v = *(const int4*)&counts[idx];
        v0 = v.x; v1 = v.y; v2 = v.z; v3 = v.w;
    } else {
        if (idx + 0 < N_NODES) v0 = counts[idx + 0];
        if (idx + 1 < N_NODES) v1 = counts[idx + 1];
        if (idx + 2 < N_NODES) v2 = counts[idx + 2];
    }
    int s0 = v0, s1 = s0 + v1, s2 = s1 + v2, s3 = s2 + v3;
    buf[tid] = s3;
    __syncthreads();
    for (int off = 1; off < 256; off <<= 1) {
        int t = (tid >= off) ? buf[tid - off] : 0;
        __syncthreads();
        buf[tid] += t;
        __syncthreads();
    }
    int excl = buf[tid] - s3;
    if (idx + 0 < N_NODES) pre[idx + 0] = excl + s0;
    if (idx + 1 < N_NODES) pre[idx + 1] = excl + s1;
    if (idx + 2 < N_NODES) pre[idx + 2] = excl + s2;
    if (idx + 3 < N_NODES) pre[idx + 3] = excl + s3;
    if (tid == 255) bsum[blockIdx.x] = buf[255];
}

__global__ __launch_bounds__(256) void scan23_kernel(const int* __restrict__ pre,
                                                     const int* __restrict__ bsum,
                                                     int* __restrict__ row_ptr) {
    __shared__ int bq[64];
    int tid = threadIdx.x;
    if (tid < 64) {
        int v = (tid < SCAN_B) ? bsum[tid] : 0;
        int orig = v;
#pragma unroll
        for (int off = 1; off < 64; off <<= 1) {
            int t = __shfl_up(v, off, 64);
            if (tid >= off) v += t;
        }
        bq[tid] = v - orig;
    }
    __syncthreads();
    int add = bq[blockIdx.x];
    int idx = blockIdx.x * 1024 + tid * 4;
#pragma unroll
    for (int u = 0; u < 4; u++) {
        int i = idx + u;
        if (i < N_NODES) row_ptr[i + 1] = pre[i] + add;
    }
    if (blockIdx.x == 0 && tid == 0) row_ptr[0] = 0;
}

// ---------------- fused scatter + layer-0 GEMM (LDS-free, barrier-free) ----------
// blocks [0, SC_B): esrc[rowptr[dst]+rank] = src.
// blocks [SC_B, ...): 64 rows x 528 cols, 8 waves; A/B frags loaded DIRECTLY
// global->VGPR (lane-contiguous 16B), software-pipelined; no LDS, no barriers.

#define SC_B ((N_EDGES + 511) / 512)
#define GB0 (M_PAD / 64)

__global__ __launch_bounds__(512) void scat_gemm0_kernel(
        const int* __restrict__ src, const int* __restrict__ dst,
        const int* __restrict__ row_ptr, const int* __restrict__ rank,
        int* __restrict__ esrc,
        const _Float16* __restrict__ A16, const _Float16* __restrict__ WtL0,
        _Float16* __restrict__ feat16, _Float16* __restrict__ res16,
        float* __restrict__ el, float* __restrict__ er) {
    if (blockIdx.x < SC_B) {
        int e = blockIdx.x * 512 + threadIdx.x;
        if (e < N_EDGES) {
            int d = dst[e];
            esrc[row_ptr[d] + rank[e]] = src[e];
        }
        return;
    }
    int tid = threadIdx.x;
    int w = tid >> 6;
    int lane = tid & 63;
    int lrow = lane & 15;
    int lk = lane >> 4;
    int row0 = (blockIdx.x - SC_B) * 64;

    f32x4 acc[4][4] = {};
    f32x4 acc5[4] = {};
    bool do5 = (w == 3);

    const _Float16* Arow[4];
#pragma unroll
    for (int m = 0; m < 4; m++)
        Arow[m] = A16 + (size_t)(row0 + m * 16 + lrow) * F_INPUT + lk * 8;
    const _Float16* Brow[4];
#pragma unroll
    for (int j = 0; j < 4; j++)
        Brow[j] = WtL0 + (size_t)((w * 4 + j) * 16 + lrow) * F_INPUT + lk * 8;
    const _Float16* B5row = WtL0 + (size_t)(512 + lrow) * F_INPUT + lk * 8;

    half8 a[4], b[4], b5;
#pragma unroll
    for (int m = 0; m < 4; m++) a[m] = *(const half8*)(Arow[m]);
#pragma unroll
    for (int j = 0; j < 4; j++) b[j] = *(const half8*)(Brow[j]);
    if (do5) b5 = *(const half8*)(B5row);

    for (int k0 = 0; k0 < F_INPUT; k0 += 32) {
        half8 an[4], bn[4], b5n;
        if (k0 + 32 < F_INPUT) {
#pragma unroll
            for (int m = 0; m < 4; m++) an[m] = *(const half8*)(Arow[m] + k0 + 32);
#pragma unroll
            for (int j = 0; j < 4; j++) bn[j] = *(const half8*)(Brow[j] + k0 + 32);
            if (do5) b5n = *(const half8*)(B5row + k0 + 32);
        }
#pragma unroll
        for (int m = 0; m < 4; m++)
#pragma unroll
            for (int j = 0; j < 4; j++)
                acc[m][j] = __builtin_amdgcn_mfma_f32_16x16x32_f16(a[m], b[j], acc[m][j], 0, 0, 0);
        if (do5) {
#pragma unroll
            for (int m = 0; m < 4; m++)
                acc5[m] = __builtin_amdgcn_mfma_f32_16x16x32_f16(a[m], b5, acc5[m], 0, 0, 0);
        }
#pragma unroll
        for (int m = 0; m < 4; m++) a[m] = an[m];
#pragma unroll
        for (int j = 0; j < 4; j++) b[j] = bn[j];
        if (do5) b5 = b5n;
    }

    if (w < 4) {
#pragma unroll
        for (int m = 0; m < 4; m++) {
#pragma unroll
            for (int r = 0; r < 4; r++) {
                int row = row0 + m * 16 + lk * 4 + r;
                if (row < N_NODES) {
#pragma unroll
                    for (int j = 0; j < 4; j++)
                        feat16[(size_t)row * HID + w * 64 + j * 16 + lrow] = (_Float16)acc[m][j][r];
                }
            }
        }
        if (w == 3 && lrow < 8) {
#pragma unroll
            for (int m = 0; m < 4; m++) {
#pragma unroll
                for (int r = 0; r < 4; r++) {
                    int row = row0 + m * 16 + lk * 4 + r;
                    if (row < N_NODES) {
                        float v = acc5[m][r];
                        if (lrow < 4) el[row * 4 + lrow] = v;
                        else          er[row * 4 + (lrow - 4)] = v;
                    }
                }
            }
        }
    } else {
        int wc = w - 4;
#pragma unroll
        for (int m = 0; m < 4; m++) {
#pragma unroll
            for (int r = 0; r < 4; r++) {
                int row = row0 + m * 16 + lk * 4 + r;
                if (row < N_NODES) {
#pragma unroll
                    for (int j = 0; j < 4; j++)
                        res16[(size_t)row * HID + wc * 64 + j * 16 + lrow] = (_Float16)acc[m][j][r];
                }
            }
        }
    }
}

// layers 1/2: C[M x 256(+elr)] = A16[M x 256] * Wt^T. 128 rows x 256 cols per block,
// 8 waves 2(row)x4(col). LDS-free: frags direct global->VGPR, software-pipelined.
__global__ __launch_bounds__(512) void gemm_h(const _Float16* __restrict__ A16,
                                              const _Float16* __restrict__ Wt,
                                              _Float16* __restrict__ feat16,
                                              float* __restrict__ el, float* __restrict__ er) {
    int tid = threadIdx.x;
    int w = tid >> 6;
    int lane = tid & 63;
    int lrow = lane & 15;
    int lk = lane >> 4;
    int wrow = w >> 2;
    int wcol = w & 3;
    int row0 = blockIdx.x * 128;

    f32x4 acc[4][4] = {};
    f32x4 acc5[4] = {};
    bool do5 = (wcol == 3);

    const _Float16* Arow[4];
#pragma unroll
    for (int m = 0; m < 4; m++)
        Arow[m] = A16 + (size_t)(row0 + wrow * 64 + m * 16 + lrow) * HID + lk * 8;
    const _Float16* Brow[4];
#pragma unroll
    for (int j = 0; j < 4; j++)
        Brow[j] = Wt + (size_t)(wcol * 64 + j * 16 + lrow) * HID + lk * 8;
    const _Float16* B5row = Wt + (size_t)(256 + lrow) * HID + lk * 8;

    half8 a[4], b[4], b5;
#pragma unroll
    for (int m = 0; m < 4; m++) a[m] = *(const half8*)(Arow[m]);
#pragma unroll
    for (int j = 0; j < 4; j++) b[j] = *(const half8*)(Brow[j]);
    if (do5) b5 = *(const half8*)(B5row);

    for (int k0 = 0; k0 < HID; k0 += 32) {
        half8 an[4], bn[4], b5n;
        if (k0 + 32 < HID) {
#pragma unroll
            for (int m = 0; m < 4; m++) an[m] = *(const half8*)(Arow[m] + k0 + 32);
#pragma unroll
            for (int j = 0; j < 4; j++) bn[j] = *(const half8*)(Brow[j] + k0 + 32);
            if (do5) b5n = *(const half8*)(B5row + k0 + 32);
        }
#pragma unroll
        for (int m = 0; m < 4; m++)
#pragma unroll
            for (int j = 0; j < 4; j++)
                acc[m][j] = __builtin_amdgcn_mfma_f32_16x16x32_f16(a[m], b[j], acc[m][j], 0, 0, 0);
        if (do5) {
#pragma unroll
            for (int m = 0; m < 4; m++)
                acc5[m] = __builtin_amdgcn_mfma_f32_16x16x32_f16(a[m], b5, acc5[m], 0, 0, 0);
        }
#pragma unroll
        for (int m = 0; m < 4; m++) a[m] = an[m];
#pragma unroll
        for (int j = 0; j < 4; j++) b[j] = bn[j];
        if (do5) b5 = b5n;
    }

#pragma unroll
    for (int m = 0; m < 4; m++) {
#pragma unroll
        for (int r = 0; r < 4; r++) {
            int row = row0 + wrow * 64 + m * 16 + lk * 4 + r;
            if (row < N_NODES) {
#pragma unroll
                for (int j = 0; j < 4; j++)
                    feat16[(size_t)row * HID + wcol * 64 + j * 16 + lrow] = (_Float16)acc[m][j][r];
            }
        }
    }
    if (wcol == 3 && lrow < 8) {
#pragma unroll
        for (int m = 0; m < 4; m++) {
#pragma unroll
            for (int r = 0; r < 4; r++) {
                int row = row0 + wrow * 64 + m * 16 + lk * 4 + r;
                if (row < N_NODES) {
                    float v = acc5[m][r];
                    if (lrow < 4) el[row * 4 + lrow] = v;
                    else          er[row * 4 + (lrow - 4)] = v;
                }
            }
        }
    }
}

// ---------------- softmax + aggregation + epilogue (measured-best R7 version) ------

__global__ __launch_bounds__(256) void agg_kernel(const _Float16* __restrict__ feat16,
                                                  const float* __restrict__ el,
                                                  const float* __restrict__ er,
                                                  const int* __restrict__ row_ptr,
                                                  const int* __restrict__ esrc,
                                                  const _Float16* __restrict__ res16,
                                                  const float* __restrict__ bias,
                                                  _Float16* __restrict__ out16,
                                                  float* __restrict__ outmean,
                                                  int do_relu) {
    __shared__ float lds[4][4 * 65 + 64];
    int wv = threadIdx.x >> 6;
    int lane = threadIdx.x & 63;
    int n = blockIdx.x * 4 + wv;
    int li = lane & 31;
    int sub = lane >> 5;
    int head = li >> 3;
    int start = row_ptr[n];
    int deg = row_ptr[n + 1] - start;
    f32x4 ern = *(const f32x4*)&er[n * 4];
    float* L = lds[wv];
    float* Loff = L + 4 * 65;
    const float* Lex = L + head * 65;

    f32x4 accA = {0.f, 0.f, 0.f, 0.f};
    f32x4 accB = {0.f, 0.f, 0.f, 0.f};
    f32x4 sm4 = {0.f, 0.f, 0.f, 0.f};
    const char* fbase = (const char*)feat16 + li * 16;

    for (int base = 0; base < deg; base += 64) {
        int e = base + lane;
        f32x4 ex4 = {0.f, 0.f, 0.f, 0.f};
        int off = 0;
        if (e < deg) {
            int s = esrc[start + e];
            off = s * (HID * 2);
            f32x4 v = *(const f32x4*)&el[s * 4];
            v = v + ern;
            v.x = v.x > 0.f ? v.x : 0.2f * v.x;
            v.y = v.y > 0.f ? v.y : 0.2f * v.y;
            v.z = v.z > 0.f ? v.z : 0.2f * v.z;
            v.w = v.w > 0.f ? v.w : 0.2f * v.w;
            ex4.x = __expf(v.x);
            ex4.y = __expf(v.y);
            ex4.z = __expf(v.z);
            ex4.w = __expf(v.w);
        }
        L[0 * 65 + lane] = ex4.x;
        L[1 * 65 + lane] = ex4.y;
        L[2 * 65 + lane] = ex4.z;
        L[3 * 65 + lane] = ex4.w;
        Loff[lane] = __int_as_float(off);
        sm4 += ex4;

        int cnt = min(64, deg - base);
        int cnt16 = (cnt + 15) & ~15;
        for (int j = 0; j < cnt16; j += 16) {
            float ex[8]; int o[8];
#pragma unroll
            for (int u = 0; u < 8; u++) {
                int e2 = j + u * 2 + sub;
                ex[u] = Lex[e2];
                o[u] = __float_as_int(Loff[e2]);
            }
            half8 f[8];
#pragma unroll
            for (int u = 0; u < 8; u++) f[u] = *(const half8*)(fbase + o[u]);
#pragma unroll
            for (int u = 0; u < 8; u++) {
                accA.x += ex[u] * (float)f[u][0];
                accA.y += ex[u] * (float)f[u][1];
                accA.z += ex[u] * (float)f[u][2];
                accA.w += ex[u] * (float)f[u][3];
                accB.x += ex[u] * (float)f[u][4];
                accB.y += ex[u] * (float)f[u][5];
                accB.z += ex[u] * (float)f[u][6];
                accB.w += ex[u] * (float)f[u][7];
            }
        }
    }

    accA.x += __shfl_xor(accA.x, 32, 64);
    accA.y += __shfl_xor(accA.y, 32, 64);
    accA.z += __shfl_xor(accA.z, 32, 64);
    accA.w += __shfl_xor(accA.w, 32, 64);
    accB.x += __shfl_xor(accB.x, 32, 64);
    accB.y += __shfl_xor(accB.y, 32, 64);
    accB.z += __shfl_xor(accB.z, 32, 64);
    accB.w += __shfl_xor(accB.w, 32, 64);

#pragma unroll
    for (int off2 = 1; off2 < 64; off2 <<= 1) {
        sm4.x += __shfl_xor(sm4.x, off2, 64);
        sm4.y += __shfl_xor(sm4.y, off2, 64);
        sm4.z += __shfl_xor(sm4.z, off2, 64);
        sm4.w += __shfl_xor(sm4.w, off2, 64);
    }
    float smh = (head == 0) ? sm4.x : (head == 1) ? sm4.y : (head == 2) ? sm4.z : sm4.w;
    float inv = 1.f / fmaxf(smh, 1e-16f);
    accA *= inv;
    accB *= inv;

    half8 rv = *(const half8*)&res16[(size_t)n * HID + li * 8];
    f32x4 bvA = *(const f32x4*)&bias[li * 8];
    f32x4 bvB = *(const f32x4*)&bias[li * 8 + 4];
    accA.x += (float)rv[0] + bvA.x;
    accA.y += (float)rv[1] + bvA.y;
    accA.z += (float)rv[2] + bvA.z;
    accA.w += (float)rv[3] + bvA.w;
    accB.x += (float)rv[4] + bvB.x;
    accB.y += (float)rv[5] + bvB.y;
    accB.z += (float)rv[6] + bvB.z;
    accB.w += (float)rv[7] + bvB.w;
    if (do_relu) {
        accA.x = fmaxf(accA.x, 0.f); accA.y = fmaxf(accA.y, 0.f);
        accA.z = fmaxf(accA.z, 0.f); accA.w = fmaxf(accA.w, 0.f);
        accB.x = fmaxf(accB.x, 0.f); accB.y = fmaxf(accB.y, 0.f);
        accB.z = fmaxf(accB.z, 0.f); accB.w = fmaxf(accB.w, 0.f);
    }
    if (outmean) {
#pragma unroll
        for (int st = 8; st <= 16; st <<= 1) {
            accA.x += __shfl_xor(accA.x, st, 64);
            accA.y += __shfl_xor(accA.y, st, 64);
            accA.z += __shfl_xor(accA.z, st, 64);
            accA.w += __shfl_xor(accA.w, st, 64);
            accB.x += __shfl_xor(accB.x, st, 64);
            accB.y += __shfl_xor(accB.y, st, 64);
            accB.z += __shfl_xor(accB.z, st, 64);
            accB.w += __shfl_xor(accB.w, st, 64);
        }
        if (sub == 0 && li < 8) {
            f32x4 moA = accA * 0.25f;
            f32x4 moB = accB * 0.25f;
            *(f32x4*)&outmean[(size_t)n * DHID + li * 8] = moA;
            *(f32x4*)&outmean[(size_t)n * DHID + li * 8 + 4] = moB;
        }
    } else {
        if (sub == 0) {
            half8 h = {(_Float16)accA.x, (_Float16)accA.y, (_Float16)accA.z, (_Float16)accA.w,
                       (_Float16)accB.x, (_Float16)accB.y, (_Float16)accB.z, (_Float16)accB.w};
            *(half8*)&out16[(size_t)n * HID + li * 8] = h;
        }
    }
}

// ---------------- launch ----------------

extern "C" void kernel_launch(void* const* d_in, const int* in_sizes, int n_in,
                              void* d_out, int out_size, void* d_ws, size_t ws_size,
                              hipStream_t stream) {
    const float* x     = (const float*)d_in[0];
    const int*   ei    = (const int*)d_in[1];
    const float* W0    = (const float*)d_in[2];
    const float* W1    = (const float*)d_in[3];
    const float* W2    = (const float*)d_in[4];
    const float* al0   = (const float*)d_in[5];
    const float* al1   = (const float*)d_in[6];
    const float* al2   = (const float*)d_in[7];
    const float* ar0   = (const float*)d_in[8];
    const float* ar1   = (const float*)d_in[9];
    const float* ar2   = (const float*)d_in[10];
    const float* b0    = (const float*)d_in[11];
    const float* b1    = (const float*)d_in[12];
    const float* b2    = (const float*)d_in[13];
    const float* resW0 = (const float*)d_in[14];
    float* out = (float*)d_out;

    const int* srcp = ei;
    const int* dstp = ei + N_EDGES;

    char* p = (char*)d_ws;
    auto alloc = [&](size_t bytes) -> char* {
        char* r = p;
        p += (bytes + 255) & ~(size_t)255;
        return r;
    };
    _Float16*  h16    = (_Float16*)alloc((size_t)M_PAD * HID * 2);
    _Float16*  feat16 = (_Float16*)alloc((size_t)M_PAD * HID * 2);
    _Float16*  res0   = (_Float16*)alloc((size_t)N_NODES * HID * 2);
    _Float16*  x16    = (_Float16*)alloc((size_t)M_PAD * F_INPUT * 2);
    float*     el     = (float*)alloc((size_t)N_NODES * HEADS * 4);
    float*     er     = (float*)alloc((size_t)N_NODES * HEADS * 4);
    _Float16*  WtL0   = (_Float16*)alloc((size_t)528 * F_INPUT * 2);
    _Float16*  Wt1    = (_Float16*)alloc((size_t)272 * HID * 2);
    _Float16*  Wt2    = (_Float16*)alloc((size_t)272 * HID * 2);
    int*       counts = (int*)alloc((size_t)N_NODES * 4);
    int*       rank   = (int*)alloc((size_t)N_EDGES * 4);
    int*       rowptr = (int*)alloc((size_t)(N_NODES + 1) * 4);
    int*       esrc   = (int*)alloc((size_t)N_EDGES * 4);
    int*       pre    = (int*)alloc((size_t)N_NODES * 4);
    int*       bsum   = (int*)alloc((size_t)SCAN_B * 4);

    const int NB = N_NODES / 4;

    hipMemsetAsync(counts, 0, (size_t)N_NODES * 4, stream);
    hist_prep_kernel<<<EB_BLOCKS + PB_BLOCKS, 256, 0, stream>>>(
        dstp, counts, rank, x, x16, W0, resW0, WtL0, W1, Wt1, W2, Wt2,
        al0, ar0, al1, ar1, al2, ar2);
    scan1_kernel<<<SCAN_B, 256, 0, stream>>>(counts, pre, bsum);
    scan23_kernel<<<SCAN_B, 256, 0, stream>>>(pre, bsum, rowptr);

    scat_gemm0_kernel<<<SC_B + GB0, 512, 0, stream>>>(
        srcp, dstp, rowptr, rank, esrc, x16, WtL0, feat16, res0, el, er);
    agg_kernel<<<NB, 256, 0, stream>>>(feat16, el, er, rowptr, esrc, res0, b0, h16, nullptr, 1);

    gemm_h<<<M_PAD / 128, 512, 0, stream>>>(h16, Wt1, feat16, el, er);
    agg_kernel<<<NB, 256, 0, stream>>>(feat16, el, er, rowptr, esrc, h16, b1, h16, nullptr, 1);

    gemm_h<<<M_PAD / 128, 512, 0, stream>>>(h16, Wt2, feat16, el, er);
    agg_kernel<<<NB, 256, 0, stream>>>(feat16, el, er, rowptr, esrc, h16, b2, nullptr, out, 0);
}

// Round 12
// 441.756 us; speedup vs baseline: 1.0615x; 1.0615x over previous
//
#include <hip/hip_runtime.h>
#include <math.h>

#define N_NODES 50000
#define N_EDGES 800000
#define F_INPUT 128
#define HEADS 4
#define DHID 64
#define HID 256          // HEADS*DHID
#define M_PAD 50048      // 782*64 = 391*128
#define SCAN_B 49        // ceil(50000/1024)

typedef _Float16 half8 __attribute__((ext_vector_type(8)));
typedef _Float16 half4 __attribute__((ext_vector_type(4)));
typedef float f32x4 __attribute__((ext_vector_type(4)));

// ---------------- fused hist + prep ----------------

#define EB_BLOCKS ((N_EDGES + 255) / 256)
#define PREP_A 1600000
#define PREP_B (PREP_A + 196608)
#define PREP_C (PREP_B + 10240)
#define PB_BLOCKS ((PREP_C + 255) / 256)

__global__ void hist_prep_kernel(const int* __restrict__ dst, int* __restrict__ counts,
                                 int* __restrict__ rank,
                                 const float* __restrict__ x, _Float16* __restrict__ x16,
                                 const float* __restrict__ W0, const float* __restrict__ WR,
                                 _Float16* __restrict__ WtL0,
                                 const float* __restrict__ W1, _Float16* __restrict__ Wt1,
                                 const float* __restrict__ W2, _Float16* __restrict__ Wt2,
                                 const float* __restrict__ al0, const float* __restrict__ ar0,
                                 const float* __restrict__ al1, const float* __restrict__ ar1,
                                 const float* __restrict__ al2, const float* __restrict__ ar2) {
    if (blockIdx.x < EB_BLOCKS) {
        int e = blockIdx.x * 256 + threadIdx.x;
        if (e < N_EDGES) rank[e] = atomicAdd(&counts[dst[e]], 1);
        return;
    }
    int t = (blockIdx.x - EB_BLOCKS) * 256 + threadIdx.x;
    if (t < PREP_A) {
        f32x4 v = *(const f32x4*)&x[t * 4];
        half4 h = {(_Float16)v.x, (_Float16)v.y, (_Float16)v.z, (_Float16)v.w};
        *(half4*)&x16[(size_t)t * 4] = h;
    } else if (t < PREP_B) {
        int u = t - PREP_A;
        if (u < 65536) {
            int c = u >> 7;
            int k = u & 127;
            float v = (c < 256) ? W0[k * 256 + c] : WR[k * 256 + (c - 256)];
            WtL0[u] = (_Float16)v;
        } else if (u < 131072) {
            int w = u - 65536;
            int c = w >> 8;
            int k = w & 255;
            Wt1[w] = (_Float16)W1[k * 256 + c];
        } else {
            int w = u - 131072;
            int c = w >> 8;
            int k = w & 255;
            Wt2[w] = (_Float16)W2[k * 256 + c];
        }
    } else if (t < PREP_C) {
        int u = t - PREP_B;
        if (u < 2048) {
            int row8 = u >> 7, k = u & 127;
            int h = row8 & 3;
            const float* vec = (row8 < 4) ? al0 : ar0;
            float s = 0.f;
            for (int d = 0; d < 64; d++) s += W0[k * 256 + h * 64 + d] * vec[h * 64 + d];
            WtL0[(512 + row8) * 128 + k] = (_Float16)s;
        } else if (u < 6144) {
            int w = u - 2048;
            int row8 = w >> 8, k = w & 255;
            int h = row8 & 3;
            const float* vec = (row8 < 4) ? al1 : ar1;
            float s = 0.f;
            for (int d = 0; d < 64; d++) s += W1[k * 256 + h * 64 + d] * vec[h * 64 + d];
            Wt1[(256 + row8) * 256 + k] = (_Float16)s;
        } else {
            int w = u - 6144;
            int row8 = w >> 8, k = w & 255;
            int h = row8 & 3;
            const float* vec = (row8 < 4) ? al2 : ar2;
            float s = 0.f;
            for (int d = 0; d < 64; d++) s += W2[k * 256 + h * 64 + d] * vec[h * 64 + d];
            Wt2[(256 + row8) * 256 + k] = (_Float16)s;
        }
    }
}

// ---------------- CSR scan ----------------

__global__ __launch_bounds__(256) void scan1_kernel(const int* __restrict__ counts,
                                                    int* __restrict__ pre,
                                                    int* __restrict__ bsum) {
    __shared__ int buf[256];
    int tid = threadIdx.x;
    int idx = blockIdx.x * 1024 + tid * 4;
    int v0 = 0, v1 = 0, v2 = 0, v3 = 0;
    if (idx + 3 < N_NODES) {
        int4 v = *(const int4*)&counts[idx];
        v0 = v.x; v1 = v.y; v2 = v.z; v3 = v.w;
    } else {
        if (idx + 0 < N_NODES) v0 = counts[idx + 0];
        if (idx + 1 < N_NODES) v1 = counts[idx + 1];
        if (idx + 2 < N_NODES) v2 = counts[idx + 2];
    }
    int s0 = v0, s1 = s0 + v1, s2 = s1 + v2, s3 = s2 + v3;
    buf[tid] = s3;
    __syncthreads();
    for (int off = 1; off < 256; off <<= 1) {
        int t = (tid >= off) ? buf[tid - off] : 0;
        __syncthreads();
        buf[tid] += t;
        __syncthreads();
    }
    int excl = buf[tid] - s3;
    if (idx + 0 < N_NODES) pre[idx + 0] = excl + s0;
    if (idx + 1 < N_NODES) pre[idx + 1] = excl + s1;
    if (idx + 2 < N_NODES) pre[idx + 2] = excl + s2;
    if (idx + 3 < N_NODES) pre[idx + 3] = excl + s3;
    if (tid == 255) bsum[blockIdx.x] = buf[255];
}

__global__ __launch_bounds__(256) void scan23_kernel(const int* __restrict__ pre,
                                                     const int* __restrict__ bsum,
                                                     int* __restrict__ row_ptr) {
    __shared__ int bq[64];
    int tid = threadIdx.x;
    if (tid < 64) {
        int v = (tid < SCAN_B) ? bsum[tid] : 0;
        int orig = v;
#pragma unroll
        for (int off = 1; off < 64; off <<= 1) {
            int t = __shfl_up(v, off, 64);
            if (tid >= off) v += t;
        }
        bq[tid] = v - orig;
    }
    __syncthreads();
    int add = bq[blockIdx.x];
    int idx = blockIdx.x * 1024 + tid * 4;
#pragma unroll
    for (int u = 0; u < 4; u++) {
        int i = idx + u;
        if (i < N_NODES) row_ptr[i + 1] = pre[i] + add;
    }
    if (blockIdx.x == 0 && tid == 0) row_ptr[0] = 0;
}

// ---------------- MFMA GEMM helpers ----------------

__device__ __forceinline__ void gl2lds16(const void* g, void* l) {
    __builtin_amdgcn_global_load_lds((const __attribute__((address_space(1))) void*)g,
                                     (__attribute__((address_space(3))) void*)l, 16, 0, 0);
}

// ---------------- fused layer-0 GEMM + scatter ----------------
// blocks [0, GB0): gemm_l0 body (64 rows x 528 cols, 8 waves) — long blocks first.
// blocks [GB0, GB0+SC_B): esrc[rowptr[dst]+rank] = src (atomic-free scatter) —
// short latency-bound blocks fill in behind the MFMA blocks.

#define SC_B ((N_EDGES + 511) / 512)
#define GB0 (M_PAD / 64)

__global__ __launch_bounds__(512) void scat_gemm0_kernel(
        const int* __restrict__ src, const int* __restrict__ dst,
        const int* __restrict__ row_ptr, const int* __restrict__ rank,
        int* __restrict__ esrc,
        const _Float16* __restrict__ A16, const _Float16* __restrict__ WtL0,
        _Float16* __restrict__ feat16, _Float16* __restrict__ res16,
        float* __restrict__ el, float* __restrict__ er) {
    if (blockIdx.x >= GB0) {
        int e = (blockIdx.x - GB0) * 512 + threadIdx.x;
        if (e < N_EDGES) {
            int d = dst[e];
            esrc[row_ptr[d] + rank[e]] = src[e];
        }
        return;
    }
    __shared__ __align__(16) _Float16 As[4 * 512];
    __shared__ __align__(16) _Float16 Ws[33 * 512];
    int tid = threadIdx.x;
    int w = tid >> 6;
    int lane = tid & 63;
    int lrow = lane & 15;
    int lk = lane >> 4;
    int row0 = blockIdx.x * 64;

    f32x4 acc[4][4] = {};
    f32x4 acc5[4] = {};

    for (int k0 = 0; k0 < F_INPUT; k0 += 32) {
        if (w < 4)
            gl2lds16(A16 + (size_t)(row0 + w * 16 + lrow) * F_INPUT + k0 + lk * 8, &As[w * 512]);
#pragma unroll
        for (int i = 0; i < 4; i++) {
            int tt = i * 8 + w;
            gl2lds16(WtL0 + (size_t)(tt * 16 + lrow) * F_INPUT + k0 + lk * 8, &Ws[tt * 512]);
        }
        if (w == 7)
            gl2lds16(WtL0 + (size_t)(512 + lrow) * F_INPUT + k0 + lk * 8, &Ws[32 * 512]);
        __syncthreads();
        half8 a[4], b[4], b5;
#pragma unroll
        for (int m = 0; m < 4; m++) a[m] = *(const half8*)&As[m * 512 + lane * 8];
#pragma unroll
        for (int j = 0; j < 4; j++) b[j] = *(const half8*)&Ws[(w * 4 + j) * 512 + lane * 8];
        if (w == 3) b5 = *(const half8*)&Ws[32 * 512 + lane * 8];
#pragma unroll
        for (int m = 0; m < 4; m++)
#pragma unroll
            for (int j = 0; j < 4; j++)
                acc[m][j] = __builtin_amdgcn_mfma_f32_16x16x32_f16(a[m], b[j], acc[m][j], 0, 0, 0);
        if (w == 3) {
#pragma unroll
            for (int m = 0; m < 4; m++)
                acc5[m] = __builtin_amdgcn_mfma_f32_16x16x32_f16(a[m], b5, acc5[m], 0, 0, 0);
        }
        __syncthreads();
    }

    if (w < 4) {
#pragma unroll
        for (int m = 0; m < 4; m++) {
#pragma unroll
            for (int r = 0; r < 4; r++) {
                int row = row0 + m * 16 + lk * 4 + r;
                if (row < N_NODES) {
#pragma unroll
                    for (int j = 0; j < 4; j++)
                        feat16[(size_t)row * HID + w * 64 + j * 16 + lrow] = (_Float16)acc[m][j][r];
                }
            }
        }
        if (w == 3 && lrow < 8) {
#pragma unroll
            for (int m = 0; m < 4; m++) {
#pragma unroll
                for (int r = 0; r < 4; r++) {
                    int row = row0 + m * 16 + lk * 4 + r;
                    if (row < N_NODES) {
                        float v = acc5[m][r];
                        if (lrow < 4) el[row * 4 + lrow] = v;
                        else          er[row * 4 + (lrow - 4)] = v;
                    }
                }
            }
        }
    } else {
        int wc = w - 4;
#pragma unroll
        for (int m = 0; m < 4; m++) {
#pragma unroll
            for (int r = 0; r < 4; r++) {
                int row = row0 + m * 16 + lk * 4 + r;
                if (row < N_NODES) {
#pragma unroll
                    for (int j = 0; j < 4; j++)
                        res16[(size_t)row * HID + wc * 64 + j * 16 + lrow] = (_Float16)acc[m][j][r];
                }
            }
        }
    }
}

// layers 1/2: C[M x 256(+elr)] = A16[M x 256] * Wt^T. 128 rows x 256 cols per block,
// 8 waves 2(row)x4(col). BK=64: two k-chunks staged per barrier pair (4 outer iters).
__global__ __launch_bounds__(512) void gemm_h(const _Float16* __restrict__ A16,
                                              const _Float16* __restrict__ Wt,
                                              _Float16* __restrict__ feat16,
                                              float* __restrict__ el, float* __restrict__ er) {
    __shared__ __align__(16) _Float16 As[8 * 2 * 512];   // [m-tile][chunk]
    __shared__ __align__(16) _Float16 Ws[17 * 2 * 512];  // [n-tile][chunk]
    int tid = threadIdx.x;
    int w = tid >> 6;
    int lane = tid & 63;
    int lrow = lane & 15;
    int lk = lane >> 4;
    int wrow = w >> 2;
    int wcol = w & 3;
    int row0 = blockIdx.x * 128;

    f32x4 acc[4][4] = {};
    f32x4 acc5[4] = {};

    for (int k0 = 0; k0 < HID; k0 += 64) {
#pragma unroll
        for (int c = 0; c < 2; c++) {
            int kk = k0 + c * 32 + lk * 8;
            gl2lds16(A16 + (size_t)(row0 + w * 16 + lrow) * HID + kk, &As[(w * 2 + c) * 512]);
            gl2lds16(Wt + (size_t)(w * 16 + lrow) * HID + kk, &Ws[(w * 2 + c) * 512]);
            gl2lds16(Wt + (size_t)((w + 8) * 16 + lrow) * HID + kk, &Ws[((w + 8) * 2 + c) * 512]);
            if (w == 0)
                gl2lds16(Wt + (size_t)(256 + lrow) * HID + kk, &Ws[(16 * 2 + c) * 512]);
        }
        __syncthreads();
#pragma unroll
        for (int c = 0; c < 2; c++) {
            half8 a[4], b[4], b5;
#pragma unroll
            for (int m = 0; m < 4; m++)
                a[m] = *(const half8*)&As[((wrow * 4 + m) * 2 + c) * 512 + lane * 8];
#pragma unroll
            for (int j = 0; j < 4; j++)
                b[j] = *(const half8*)&Ws[((wcol * 4 + j) * 2 + c) * 512 + lane * 8];
            if (wcol == 3) b5 = *(const half8*)&Ws[(16 * 2 + c) * 512 + lane * 8];
#pragma unroll
            for (int m = 0; m < 4; m++)
#pragma unroll
                for (int j = 0; j < 4; j++)
                    acc[m][j] = __builtin_amdgcn_mfma_f32_16x16x32_f16(a[m], b[j], acc[m][j], 0, 0, 0);
            if (wcol == 3) {
#pragma unroll
                for (int m = 0; m < 4; m++)
                    acc5[m] = __builtin_amdgcn_mfma_f32_16x16x32_f16(a[m], b5, acc5[m], 0, 0, 0);
            }
        }
        __syncthreads();
    }

#pragma unroll
    for (int m = 0; m < 4; m++) {
#pragma unroll
        for (int r = 0; r < 4; r++) {
            int row = row0 + wrow * 64 + m * 16 + lk * 4 + r;
            if (row < N_NODES) {
#pragma unroll
                for (int j = 0; j < 4; j++)
                    feat16[(size_t)row * HID + wcol * 64 + j * 16 + lrow] = (_Float16)acc[m][j][r];
            }
        }
    }
    if (wcol == 3 && lrow < 8) {
#pragma unroll
        for (int m = 0; m < 4; m++) {
#pragma unroll
            for (int r = 0; r < 4; r++) {
                int row = row0 + wrow * 64 + m * 16 + lk * 4 + r;
                if (row < N_NODES) {
                    float v = acc5[m][r];
                    if (lrow < 4) el[row * 4 + lrow] = v;
                    else          er[row * 4 + (lrow - 4)] = v;
                }
            }
        }
    }
}

// ---------------- softmax + aggregation + epilogue (measured-best R7 version) ------
// one wave per node. Phase 1: lane=edge, exp once (4 heads) -> LDS. Phase 2: 2 edges
// per wave-instr, 16B/lane gathers; lane li covers dims li*8..+7 (head = li>>3).
// No max-subtract (logits bounded; alpha shift-invariant). One denom tree per node.

__global__ __launch_bounds__(256) void agg_kernel(const _Float16* __restrict__ feat16,
                                                  const float* __restrict__ el,
                                                  const float* __restrict__ er,
                                                  const int* __restrict__ row_ptr,
                                                  const int* __restrict__ esrc,
                                                  const _Float16* __restrict__ res16,
                                                  const float* __restrict__ bias,
                                                  _Float16* __restrict__ out16,
                                                  float* __restrict__ outmean,
                                                  int do_relu) {
    __shared__ float lds[4][4 * 65 + 64];
    int wv = threadIdx.x >> 6;
    int lane = threadIdx.x & 63;
    int n = blockIdx.x * 4 + wv;
    int li = lane & 31;
    int sub = lane >> 5;
    int head = li >> 3;
    int start = row_ptr[n];
    int deg = row_ptr[n + 1] - start;
    f32x4 ern = *(const f32x4*)&er[n * 4];
    float* L = lds[wv];
    float* Loff = L + 4 * 65;
    const float* Lex = L + head * 65;

    f32x4 accA = {0.f, 0.f, 0.f, 0.f};
    f32x4 accB = {0.f, 0.f, 0.f, 0.f};
    f32x4 sm4 = {0.f, 0.f, 0.f, 0.f};
    const char* fbase = (const char*)feat16 + li * 16;

    for (int base = 0; base < deg; base += 64) {
        int e = base + lane;
        f32x4 ex4 = {0.f, 0.f, 0.f, 0.f};
        int off = 0;
        if (e < deg) {
            int s = esrc[start + e];
            off = s * (HID * 2);
            f32x4 v = *(const f32x4*)&el[s * 4];
            v = v + ern;
            v.x = v.x > 0.f ? v.x : 0.2f * v.x;
            v.y = v.y > 0.f ? v.y : 0.2f * v.y;
            v.z = v.z > 0.f ? v.z : 0.2f * v.z;
            v.w = v.w > 0.f ? v.w : 0.2f * v.w;
            ex4.x = __expf(v.x);
            ex4.y = __expf(v.y);
            ex4.z = __expf(v.z);
            ex4.w = __expf(v.w);
        }
        L[0 * 65 + lane] = ex4.x;
        L[1 * 65 + lane] = ex4.y;
        L[2 * 65 + lane] = ex4.z;
        L[3 * 65 + lane] = ex4.w;
        Loff[lane] = __int_as_float(off);
        sm4 += ex4;

        int cnt = min(64, deg - base);
        int cnt16 = (cnt + 15) & ~15;
        for (int j = 0; j < cnt16; j += 16) {
            float ex[8]; int o[8];
#pragma unroll
            for (int u = 0; u < 8; u++) {
                int e2 = j + u * 2 + sub;
                ex[u] = Lex[e2];
                o[u] = __float_as_int(Loff[e2]);
            }
            half8 f[8];
#pragma unroll
            for (int u = 0; u < 8; u++) f[u] = *(const half8*)(fbase + o[u]);
#pragma unroll
            for (int u = 0; u < 8; u++) {
                accA.x += ex[u] * (float)f[u][0];
                accA.y += ex[u] * (float)f[u][1];
                accA.z += ex[u] * (float)f[u][2];
                accA.w += ex[u] * (float)f[u][3];
                accB.x += ex[u] * (float)f[u][4];
                accB.y += ex[u] * (float)f[u][5];
                accB.z += ex[u] * (float)f[u][6];
                accB.w += ex[u] * (float)f[u][7];
            }
        }
    }

    accA.x += __shfl_xor(accA.x, 32, 64);
    accA.y += __shfl_xor(accA.y, 32, 64);
    accA.z += __shfl_xor(accA.z, 32, 64);
    accA.w += __shfl_xor(accA.w, 32, 64);
    accB.x += __shfl_xor(accB.x, 32, 64);
    accB.y += __shfl_xor(accB.y, 32, 64);
    accB.z += __shfl_xor(accB.z, 32, 64);
    accB.w += __shfl_xor(accB.w, 32, 64);

#pragma unroll
    for (int off2 = 1; off2 < 64; off2 <<= 1) {
        sm4.x += __shfl_xor(sm4.x, off2, 64);
        sm4.y += __shfl_xor(sm4.y, off2, 64);
        sm4.z += __shfl_xor(sm4.z, off2, 64);
        sm4.w += __shfl_xor(sm4.w, off2, 64);
    }
    float smh = (head == 0) ? sm4.x : (head == 1) ? sm4.y : (head == 2) ? sm4.z : sm4.w;
    float inv = 1.f / fmaxf(smh, 1e-16f);
    accA *= inv;
    accB *= inv;

    half8 rv = *(const half8*)&res16[(size_t)n * HID + li * 8];
    f32x4 bvA = *(const f32x4*)&bias[li * 8];
    f32x4 bvB = *(const f32x4*)&bias[li * 8 + 4];
    accA.x += (float)rv[0] + bvA.x;
    accA.y += (float)rv[1] + bvA.y;
    accA.z += (float)rv[2] + bvA.z;
    accA.w += (float)rv[3] + bvA.w;
    accB.x += (float)rv[4] + bvB.x;
    accB.y += (float)rv[5] + bvB.y;
    accB.z += (float)rv[6] + bvB.z;
    accB.w += (float)rv[7] + bvB.w;
    if (do_relu) {
        accA.x = fmaxf(accA.x, 0.f); accA.y = fmaxf(accA.y, 0.f);
        accA.z = fmaxf(accA.z, 0.f); accA.w = fmaxf(accA.w, 0.f);
        accB.x = fmaxf(accB.x, 0.f); accB.y = fmaxf(accB.y, 0.f);
        accB.z = fmaxf(accB.z, 0.f); accB.w = fmaxf(accB.w, 0.f);
    }
    if (outmean) {
#pragma unroll
        for (int st = 8; st <= 16; st <<= 1) {
            accA.x += __shfl_xor(accA.x, st, 64);
            accA.y += __shfl_xor(accA.y, st, 64);
            accA.z += __shfl_xor(accA.z, st, 64);
            accA.w += __shfl_xor(accA.w, st, 64);
            accB.x += __shfl_xor(accB.x, st, 64);
            accB.y += __shfl_xor(accB.y, st, 64);
            accB.z += __shfl_xor(accB.z, st, 64);
            accB.w += __shfl_xor(accB.w, st, 64);
        }
        if (sub == 0 && li < 8) {
            f32x4 moA = accA * 0.25f;
            f32x4 moB = accB * 0.25f;
            *(f32x4*)&outmean[(size_t)n * DHID + li * 8] = moA;
            *(f32x4*)&outmean[(size_t)n * DHID + li * 8 + 4] = moB;
        }
    } else {
        if (sub == 0) {
            half8 h = {(_Float16)accA.x, (_Float16)accA.y, (_Float16)accA.z, (_Float16)accA.w,
                       (_Float16)accB.x, (_Float16)accB.y, (_Float16)accB.z, (_Float16)accB.w};
            *(half8*)&out16[(size_t)n * HID + li * 8] = h;
        }
    }
}

// ---------------- launch ----------------

extern "C" void kernel_launch(void* const* d_in, const int* in_sizes, int n_in,
                              void* d_out, int out_size, void* d_ws, size_t ws_size,
                              hipStream_t stream) {
    const float* x     = (const float*)d_in[0];
    const int*   ei    = (const int*)d_in[1];
    const float* W0    = (const float*)d_in[2];
    const float* W1    = (const float*)d_in[3];
    const float* W2    = (const float*)d_in[4];
    const float* al0   = (const float*)d_in[5];
    const float* al1   = (const float*)d_in[6];
    const float* al2   = (const float*)d_in[7];
    const float* ar0   = (const float*)d_in[8];
    const float* ar1   = (const float*)d_in[9];
    const float* ar2   = (const float*)d_in[10];
    const float* b0    = (const float*)d_in[11];
    const float* b1    = (const float*)d_in[12];
    const float* b2    = (const float*)d_in[13];
    const float* resW0 = (const float*)d_in[14];
    float* out = (float*)d_out;

    const int* srcp = ei;
    const int* dstp = ei + N_EDGES;

    char* p = (char*)d_ws;
    auto alloc = [&](size_t bytes) -> char* {
        char* r = p;
        p += (bytes + 255) & ~(size_t)255;
        return r;
    };
    _Float16*  h16    = (_Float16*)alloc((size_t)M_PAD * HID * 2);
    _Float16*  feat16 = (_Float16*)alloc((size_t)M_PAD * HID * 2);
    _Float16*  res0   = (_Float16*)alloc((size_t)N_NODES * HID * 2);
    _Float16*  x16    = (_Float16*)alloc((size_t)M_PAD * F_INPUT * 2);
    float*     el     = (float*)alloc((size_t)N_NODES * HEADS * 4);
    float*     er     = (float*)alloc((size_t)N_NODES * HEADS * 4);
    _Float16*  WtL0   = (_Float16*)alloc((size_t)528 * F_INPUT * 2);
    _Float16*  Wt1    = (_Float16*)alloc((size_t)272 * HID * 2);
    _Float16*  Wt2    = (_Float16*)alloc((size_t)272 * HID * 2);
    int*       counts = (int*)alloc((size_t)N_NODES * 4);
    int*       rank   = (int*)alloc((size_t)N_EDGES * 4);
    int*       rowptr = (int*)alloc((size_t)(N_NODES + 1) * 4);
    int*       esrc   = (int*)alloc((size_t)N_EDGES * 4);
    int*       pre    = (int*)alloc((size_t)N_NODES * 4);
    int*       bsum   = (int*)alloc((size_t)SCAN_B * 4);

    const int NB = N_NODES / 4;

    hipMemsetAsync(counts, 0, (size_t)N_NODES * 4, stream);
    hist_prep_kernel<<<EB_BLOCKS + PB_BLOCKS, 256, 0, stream>>>(
        dstp, counts, rank, x, x16, W0, resW0, WtL0, W1, Wt1, W2, Wt2,
        al0, ar0, al1, ar1, al2, ar2);
    scan1_kernel<<<SCAN_B, 256, 0, stream>>>(counts, pre, bsum);
    scan23_kernel<<<SCAN_B, 256, 0, stream>>>(pre, bsum, rowptr);

    // fused: layer-0 GEMM (blocks [0,GB0)) + atomic-free scatter (blocks [GB0,..))
    scat_gemm0_kernel<<<GB0 + SC_B, 512, 0, stream>>>(
        srcp, dstp, rowptr, rank, esrc, x16, WtL0, feat16, res0, el, er);
    agg_kernel<<<NB, 256, 0, stream>>>(feat16, el, er, rowptr, esrc, res0, b0, h16, nullptr, 1);

    gemm_h<<<M_PAD / 128, 512, 0, stream>>>(h16, Wt1, feat16, el, er);
    agg_kernel<<<NB, 256, 0, stream>>>(feat16, el, er, rowptr, esrc, h16, b1, h16, nullptr, 1);

    gemm_h<<<M_PAD / 128, 512, 0, stream>>>(h16, Wt2, feat16, el, er);
    agg_kernel<<<NB, 256, 0, stream>>>(feat16, el, er, rowptr, esrc, h16, b2, nullptr, out, 0);
}